// Round 1
// baseline (1776.843 us; speedup 1.0000x reference)
//
#include <hip/hip_runtime.h>

#define NN 50000
#define EE 800000

__device__ __forceinline__ unsigned mapf(float f) {
    unsigned u = __float_as_uint(f);
    return (u & 0x80000000u) ? ~u : (u | 0x80000000u);
}
__device__ __forceinline__ float unmapf(unsigned u) {
    return __uint_as_float((u & 0x80000000u) ? (u ^ 0x80000000u) : ~u);
}
__device__ __forceinline__ float swishf(float v) {
    return v / (1.f + __expf(-v));
}

// ---------------- q/k projection: q = x @ Wq, k = x @ Wk (64x64 weights) ------
__global__ void __launch_bounds__(256) qk_kernel(
    const float* __restrict__ x, const float* __restrict__ Wq, const float* __restrict__ Wk,
    float* __restrict__ q, float* __restrict__ k)
{
    __shared__ float sWq[64 * 64];
    __shared__ float sWk[64 * 64];
    __shared__ float xrow[4][64];
    for (int i = threadIdx.x; i < 4096; i += 256) { sWq[i] = Wq[i]; sWk[i] = Wk[i]; }
    __syncthreads();
    const int lane = threadIdx.x & 63;
    const int winb = threadIdx.x >> 6;
    const int wave = (blockIdx.x * 256 + threadIdx.x) >> 6;
    const int nw = gridDim.x * 4;
    for (int row = wave; row < NN; row += nw) {
        xrow[winb][lane] = x[row * 64 + lane];
        float aq = 0.f, ak = 0.f;
#pragma unroll
        for (int b = 0; b < 64; ++b) {
            float xb = xrow[winb][b];
            aq = fmaf(xb, sWq[b * 64 + lane], aq);
            ak = fmaf(xb, sWk[b * 64 + lane], ak);
        }
        q[row * 64 + lane] = aq;
        k[row * 64 + lane] = ak;
    }
}

// ---------------- edge pass A: logits + segment max (atomicMax on mapped uint) -
__global__ void __launch_bounds__(256) edgeA_kernel(
    const float* __restrict__ q, const float* __restrict__ k,
    const float* __restrict__ edges, const int* __restrict__ senders,
    const int* __restrict__ receivers, const float* __restrict__ Wa,
    float* __restrict__ logits, unsigned* __restrict__ maxs)
{
    const int lane = threadIdx.x & 63;
    const int wave = (blockIdx.x * 256 + threadIdx.x) >> 6;
    const int nw = gridDim.x * 4;
    const float wa = Wa[lane];
    const float wa64 = Wa[64];
    for (int e = wave; e < EE; e += nw) {
        int s = senders[e];
        int r = receivers[e];
        float z = q[s * 64 + lane] + k[r * 64 + lane];
        float f = swishf(z);
        float p = f * wa;
#pragma unroll
        for (int m = 32; m; m >>= 1) p += __shfl_xor(p, m);
        if (lane == 0) {
            float logit = fmaf(edges[e], wa64, p);
            logits[e] = logit;
            atomicMax(maxs + r, mapf(logit));
        }
    }
}

// ---------------- edge pass B: w=exp(logit-max); accumulate num/denom ---------
__global__ void __launch_bounds__(256) edgeB_kernel(
    const float* __restrict__ q, const float* __restrict__ logits,
    const unsigned* __restrict__ maxs, const int* __restrict__ senders,
    const int* __restrict__ receivers,
    float* __restrict__ num, float* __restrict__ denom)
{
    const int lane = threadIdx.x & 63;
    const int wave = (blockIdx.x * 256 + threadIdx.x) >> 6;
    const int nw = gridDim.x * 4;
    for (int e = wave; e < EE; e += nw) {
        int s = senders[e];
        int r = receivers[e];
        float w = __expf(logits[e] - unmapf(maxs[r]));
        atomicAdd(num + (size_t)r * 64 + lane, w * q[s * 64 + lane]);
        if (lane == 0) atomicAdd(denom + r, w);
    }
}

// ---------------- node update: swish(num/den) + x, optional LN ----------------
__global__ void __launch_bounds__(256) node_kernel(
    const float* __restrict__ num, const float* __restrict__ denom,
    float* __restrict__ x, const float* __restrict__ ln_s,
    const float* __restrict__ ln_b, int do_ln)
{
    const int lane = threadIdx.x & 63;
    const int wave = (blockIdx.x * 256 + threadIdx.x) >> 6;
    const int nw = gridDim.x * 4;
    for (int n = wave; n < NN; n += nw) {
        float den = denom[n];
        float v = den > 0.f ? num[(size_t)n * 64 + lane] / den : 0.f;
        float nv = swishf(v) + x[n * 64 + lane];
        if (do_ln) {
            float s = nv;
#pragma unroll
            for (int m = 32; m; m >>= 1) s += __shfl_xor(s, m);
            float mean = s * (1.f / 64.f);
            float d = nv - mean;
            float vs = d * d;
#pragma unroll
            for (int m = 32; m; m >>= 1) vs += __shfl_xor(vs, m);
            nv = d * rsqrtf(vs * (1.f / 64.f) + 1e-6f) * ln_s[lane] + ln_b[lane];
        }
        x[n * 64 + lane] = nv;
    }
}

// ---------------- fused readout MLP: 64->64->32->16->16->1 -------------------
__global__ void __launch_bounds__(256) readout_kernel(
    const float* __restrict__ x,
    const float* __restrict__ W0, const float* __restrict__ rs0, const float* __restrict__ rb0,
    const float* __restrict__ W1, const float* __restrict__ rs1, const float* __restrict__ rb1,
    const float* __restrict__ W2, const float* __restrict__ rs2, const float* __restrict__ rb2,
    const float* __restrict__ W3, const float* __restrict__ rs3, const float* __restrict__ rb3,
    const float* __restrict__ W4, float* __restrict__ out)
{
    __shared__ float sW[6928];   // W0@0 (4096), W1@4096 (2048), W2@6144 (512), W3@6656 (256), W4@6912 (16)
    __shared__ float hb[4][64];
    for (int i = threadIdx.x; i < 4096; i += 256) sW[i] = W0[i];
    for (int i = threadIdx.x; i < 2048; i += 256) sW[4096 + i] = W1[i];
    for (int i = threadIdx.x; i < 512; i += 256) sW[6144 + i] = W2[i];
    for (int i = threadIdx.x; i < 256; i += 256) sW[6656 + i] = W3[i];
    if (threadIdx.x < 16) sW[6912 + threadIdx.x] = W4[threadIdx.x];
    __syncthreads();
    const int lane = threadIdx.x & 63;
    const int winb = threadIdx.x >> 6;
    const int wave = (blockIdx.x * 256 + threadIdx.x) >> 6;
    const int nw = gridDim.x * 4;
    for (int n = wave; n < NN; n += nw) {
        hb[winb][lane] = x[(size_t)n * 64 + lane];
        // layer 0: 64 -> 64, LN64, swish
        float y = 0.f;
#pragma unroll
        for (int i = 0; i < 64; ++i) y = fmaf(hb[winb][i], sW[i * 64 + lane], y);
        {
            float s = y;
#pragma unroll
            for (int m = 32; m; m >>= 1) s += __shfl_xor(s, m);
            float mean = s * (1.f / 64.f);
            float d = y - mean;
            float vs = d * d;
#pragma unroll
            for (int m = 32; m; m >>= 1) vs += __shfl_xor(vs, m);
            y = d * rsqrtf(vs * (1.f / 64.f) + 1e-6f) * rs0[lane] + rb0[lane];
            y = swishf(y);
        }
        hb[winb][lane] = y;
        // layer 1: 64 -> 32, LN32, swish
        const int j1 = lane & 31;
        float y1 = 0.f;
#pragma unroll
        for (int i = 0; i < 64; ++i) y1 = fmaf(hb[winb][i], sW[4096 + i * 32 + j1], y1);
        {
            float s = y1;
#pragma unroll
            for (int m = 16; m; m >>= 1) s += __shfl_xor(s, m);
            float mean = s * (1.f / 32.f);
            float d = y1 - mean;
            float vs = d * d;
#pragma unroll
            for (int m = 16; m; m >>= 1) vs += __shfl_xor(vs, m);
            y1 = d * rsqrtf(vs * (1.f / 32.f) + 1e-6f) * rs1[j1] + rb1[j1];
            y1 = swishf(y1);
        }
        if (lane < 32) hb[winb][lane] = y1;
        // layer 2: 32 -> 16, LN16, swish
        const int j2 = lane & 15;
        float y2 = 0.f;
#pragma unroll
        for (int i = 0; i < 32; ++i) y2 = fmaf(hb[winb][i], sW[6144 + i * 16 + j2], y2);
        {
            float s = y2;
#pragma unroll
            for (int m = 8; m; m >>= 1) s += __shfl_xor(s, m);
            float mean = s * (1.f / 16.f);
            float d = y2 - mean;
            float vs = d * d;
#pragma unroll
            for (int m = 8; m; m >>= 1) vs += __shfl_xor(vs, m);
            y2 = d * rsqrtf(vs * (1.f / 16.f) + 1e-6f) * rs2[j2] + rb2[j2];
            y2 = swishf(y2);
        }
        if (lane < 16) hb[winb][lane] = y2;
        // layer 3: 16 -> 16, LN16, swish
        float y3 = 0.f;
#pragma unroll
        for (int i = 0; i < 16; ++i) y3 = fmaf(hb[winb][i], sW[6656 + i * 16 + j2], y3);
        {
            float s = y3;
#pragma unroll
            for (int m = 8; m; m >>= 1) s += __shfl_xor(s, m);
            float mean = s * (1.f / 16.f);
            float d = y3 - mean;
            float vs = d * d;
#pragma unroll
            for (int m = 8; m; m >>= 1) vs += __shfl_xor(vs, m);
            y3 = d * rsqrtf(vs * (1.f / 16.f) + 1e-6f) * rs3[j2] + rb3[j2];
            y3 = swishf(y3);
        }
        if (lane < 16) hb[winb][lane] = y3;
        // final: 16 -> 1, swish
        float p = (lane < 16) ? hb[winb][lane] * sW[6912 + lane] : 0.f;
#pragma unroll
        for (int m = 8; m; m >>= 1) p += __shfl_xor(p, m);
        if (lane == 0) out[n] = swishf(p);
    }
}

extern "C" void kernel_launch(void* const* d_in, const int* in_sizes, int n_in,
                              void* d_out, int out_size, void* d_ws, size_t ws_size,
                              hipStream_t stream)
{
    const float* nodes     = (const float*)d_in[0];
    const float* edges     = (const float*)d_in[1];
    const int*   senders   = (const int*)d_in[2];
    const int*   receivers = (const int*)d_in[3];
    // d_in[4] = mask (all true in this problem; where(mask,0,-inf) == 0) — ignored
    const float* Wq  = (const float*)d_in[5];
    const float* Wk  = (const float*)d_in[6];
    const float* Wa  = (const float*)d_in[7];
    const float* ln_s = (const float*)d_in[8];
    const float* ln_b = (const float*)d_in[9];
    const float* Wr0 = (const float*)d_in[10];
    const float* rs0 = (const float*)d_in[11];
    const float* rb0 = (const float*)d_in[12];
    const float* Wr1 = (const float*)d_in[13];
    const float* rs1 = (const float*)d_in[14];
    const float* rb1 = (const float*)d_in[15];
    const float* Wr2 = (const float*)d_in[16];
    const float* rs2 = (const float*)d_in[17];
    const float* rb2 = (const float*)d_in[18];
    const float* Wr3 = (const float*)d_in[19];
    const float* rs3 = (const float*)d_in[20];
    const float* rb3 = (const float*)d_in[21];
    const float* Wr4 = (const float*)d_in[22];
    float* out = (float*)d_out;

    // workspace layout (floats): x, q, k, num: N*64 each; denom: N; maxs: N; logits: E
    float* x      = (float*)d_ws;
    float* q      = x + (size_t)NN * 64;
    float* k      = q + (size_t)NN * 64;
    float* num    = k + (size_t)NN * 64;
    float* denom  = num + (size_t)NN * 64;
    unsigned* maxs = (unsigned*)(denom + NN);
    float* logits = (float*)(maxs + NN);

    hipMemcpyAsync(x, nodes, (size_t)NN * 64 * sizeof(float), hipMemcpyDeviceToDevice, stream);

    for (int l = 0; l < 4; ++l) {
        // zero num (N*64), denom (N), maxs (N) in one contiguous memset
        hipMemsetAsync(num, 0, (size_t)NN * 66 * sizeof(float), stream);
        qk_kernel<<<1024, 256, 0, stream>>>(x, Wq + l * 4096, Wk + l * 4096, q, k);
        edgeA_kernel<<<8192, 256, 0, stream>>>(q, k, edges, senders, receivers, Wa + l * 65, logits, maxs);
        edgeB_kernel<<<8192, 256, 0, stream>>>(q, logits, maxs, senders, receivers, num, denom);
        int lnidx = l < 3 ? l : 0;
        node_kernel<<<1024, 256, 0, stream>>>(num, denom, x, ln_s + lnidx * 64, ln_b + lnidx * 64, l < 3 ? 1 : 0);
    }
    readout_kernel<<<2048, 256, 0, stream>>>(x, Wr0, rs0, rb0, Wr1, rs1, rb1,
                                             Wr2, rs2, rb2, Wr3, rs3, rb3, Wr4, out);
}

// Round 2
// 1041.461 us; speedup vs baseline: 1.7061x; 1.7061x over previous
//
#include <hip/hip_runtime.h>

#define NN 50000
#define EE 800000

__device__ __forceinline__ float swishf(float v) {
    return v / (1.f + __expf(-v));
}

// ---------------- q/k projection: q = x @ Wq, k = x @ Wk (64x64 weights) ------
__global__ void __launch_bounds__(256) qk_kernel(
    const float* __restrict__ x, const float* __restrict__ Wq, const float* __restrict__ Wk,
    float* __restrict__ q, float* __restrict__ k)
{
    __shared__ float sWq[64 * 64];
    __shared__ float sWk[64 * 64];
    __shared__ float xrow[4][64];
    for (int i = threadIdx.x; i < 4096; i += 256) { sWq[i] = Wq[i]; sWk[i] = Wk[i]; }
    __syncthreads();
    const int lane = threadIdx.x & 63;
    const int winb = threadIdx.x >> 6;
    const int wave = (blockIdx.x * 256 + threadIdx.x) >> 6;
    const int nw = gridDim.x * 4;
    for (int row = wave; row < NN; row += nw) {
        xrow[winb][lane] = x[row * 64 + lane];
        float aq = 0.f, ak = 0.f;
#pragma unroll
        for (int b = 0; b < 64; ++b) {
            float xb = xrow[winb][b];
            aq = fmaf(xb, sWq[b * 64 + lane], aq);
            ak = fmaf(xb, sWk[b * 64 + lane], ak);
        }
        q[row * 64 + lane] = aq;
        k[row * 64 + lane] = ak;
    }
}

// ---------------- CSR build: histogram / scan / scatter ----------------------
__global__ void __launch_bounds__(256) hist_kernel(
    const int* __restrict__ receivers, int* __restrict__ counts)
{
    int e = blockIdx.x * 256 + threadIdx.x;
    int stride = gridDim.x * 256;
    for (; e < EE; e += stride) atomicAdd(counts + receivers[e], 1);
}

__global__ void __launch_bounds__(1024) scan_kernel(
    const int* __restrict__ counts, int* __restrict__ offsets)
{
    __shared__ int ts[1024];
    const int t = threadIdx.x;
    const int beg = t * 49;
    const int end = min(beg + 49, NN);
    int s = 0;
    for (int i = beg; i < end; ++i) s += counts[i];
    ts[t] = s;
    __syncthreads();
    // Hillis-Steele inclusive scan over 1024 thread sums
    for (int d = 1; d < 1024; d <<= 1) {
        int v = (t >= d) ? ts[t - d] : 0;
        __syncthreads();
        ts[t] += v;
        __syncthreads();
    }
    int ex = (t == 0) ? 0 : ts[t - 1];
    for (int i = beg; i < end; ++i) { offsets[i] = ex; ex += counts[i]; }
    if (t == 1023) offsets[NN] = ts[1023];
}

__global__ void __launch_bounds__(256) scatter_kernel(
    const int* __restrict__ receivers, const int* __restrict__ offsets,
    int* __restrict__ ctr, int* __restrict__ sorted)
{
    int e = blockIdx.x * 256 + threadIdx.x;
    int stride = gridDim.x * 256;
    for (; e < EE; e += stride) {
        int r = receivers[e];
        int pos = atomicAdd(ctr + r, 1);
        sorted[offsets[r] + pos] = e;
    }
}

// ---------------- fused attention layer: wave per receiver -------------------
// online softmax over the receiver's edge list; accumulate numerator in regs;
// then swish(num/den) + x and optional LayerNorm, written back to x in place.
__global__ void __launch_bounds__(256) attn_kernel(
    const float* __restrict__ q, const float* __restrict__ k,
    const float* __restrict__ edges, const int* __restrict__ senders,
    const int* __restrict__ sorted, const int* __restrict__ offsets,
    const float* __restrict__ Wa,
    float* __restrict__ x, const float* __restrict__ ln_s,
    const float* __restrict__ ln_b, int do_ln)
{
    const int lane = threadIdx.x & 63;
    const int wave = (blockIdx.x * 256 + threadIdx.x) >> 6;
    const int nw = gridDim.x * 4;
    const float wa = Wa[lane];
    const float wa64 = Wa[64];
    for (int r = wave; r < NN; r += nw) {
        const float kr = k[r * 64 + lane];
        float m = -3.0e38f, den = 0.f, acc = 0.f;
        const int beg = offsets[r], end = offsets[r + 1];
        for (int i = beg; i < end; ++i) {
            const int e = sorted[i];
            const int s = senders[e];
            const float qv = q[(size_t)s * 64 + lane];
            float p = swishf(qv + kr) * wa;
#pragma unroll
            for (int msk = 32; msk; msk >>= 1) p += __shfl_xor(p, msk);
            const float logit = fmaf(edges[e], wa64, p);   // uniform across wave
            if (logit > m) {
                const float sc = __expf(m - logit);
                den *= sc; acc *= sc; m = logit;
            }
            const float w = __expf(logit - m);
            den += w;
            acc = fmaf(w, qv, acc);
        }
        float v = den > 0.f ? acc / den : 0.f;
        float nv = swishf(v) + x[(size_t)r * 64 + lane];
        if (do_ln) {
            float s = nv;
#pragma unroll
            for (int msk = 32; msk; msk >>= 1) s += __shfl_xor(s, msk);
            const float mean = s * (1.f / 64.f);
            const float d = nv - mean;
            float vs = d * d;
#pragma unroll
            for (int msk = 32; msk; msk >>= 1) vs += __shfl_xor(vs, msk);
            nv = d * rsqrtf(vs * (1.f / 64.f) + 1e-6f) * ln_s[lane] + ln_b[lane];
        }
        x[(size_t)r * 64 + lane] = nv;
    }
}

// ---------------- fused readout MLP: 64->64->32->16->16->1 -------------------
__global__ void __launch_bounds__(256) readout_kernel(
    const float* __restrict__ x,
    const float* __restrict__ W0, const float* __restrict__ rs0, const float* __restrict__ rb0,
    const float* __restrict__ W1, const float* __restrict__ rs1, const float* __restrict__ rb1,
    const float* __restrict__ W2, const float* __restrict__ rs2, const float* __restrict__ rb2,
    const float* __restrict__ W3, const float* __restrict__ rs3, const float* __restrict__ rb3,
    const float* __restrict__ W4, float* __restrict__ out)
{
    __shared__ float sW[6928];   // W0@0 (4096), W1@4096 (2048), W2@6144 (512), W3@6656 (256), W4@6912 (16)
    __shared__ float hb[4][64];
    for (int i = threadIdx.x; i < 4096; i += 256) sW[i] = W0[i];
    for (int i = threadIdx.x; i < 2048; i += 256) sW[4096 + i] = W1[i];
    for (int i = threadIdx.x; i < 512; i += 256) sW[6144 + i] = W2[i];
    for (int i = threadIdx.x; i < 256; i += 256) sW[6656 + i] = W3[i];
    if (threadIdx.x < 16) sW[6912 + threadIdx.x] = W4[threadIdx.x];
    __syncthreads();
    const int lane = threadIdx.x & 63;
    const int winb = threadIdx.x >> 6;
    const int wave = (blockIdx.x * 256 + threadIdx.x) >> 6;
    const int nw = gridDim.x * 4;
    for (int n = wave; n < NN; n += nw) {
        hb[winb][lane] = x[(size_t)n * 64 + lane];
        // layer 0: 64 -> 64, LN64, swish
        float y = 0.f;
#pragma unroll
        for (int i = 0; i < 64; ++i) y = fmaf(hb[winb][i], sW[i * 64 + lane], y);
        {
            float s = y;
#pragma unroll
            for (int m = 32; m; m >>= 1) s += __shfl_xor(s, m);
            float mean = s * (1.f / 64.f);
            float d = y - mean;
            float vs = d * d;
#pragma unroll
            for (int m = 32; m; m >>= 1) vs += __shfl_xor(vs, m);
            y = d * rsqrtf(vs * (1.f / 64.f) + 1e-6f) * rs0[lane] + rb0[lane];
            y = swishf(y);
        }
        hb[winb][lane] = y;
        // layer 1: 64 -> 32, LN32, swish
        const int j1 = lane & 31;
        float y1 = 0.f;
#pragma unroll
        for (int i = 0; i < 64; ++i) y1 = fmaf(hb[winb][i], sW[4096 + i * 32 + j1], y1);
        {
            float s = y1;
#pragma unroll
            for (int m = 16; m; m >>= 1) s += __shfl_xor(s, m);
            float mean = s * (1.f / 32.f);
            float d = y1 - mean;
            float vs = d * d;
#pragma unroll
            for (int m = 16; m; m >>= 1) vs += __shfl_xor(vs, m);
            y1 = d * rsqrtf(vs * (1.f / 32.f) + 1e-6f) * rs1[j1] + rb1[j1];
            y1 = swishf(y1);
        }
        if (lane < 32) hb[winb][lane] = y1;
        // layer 2: 32 -> 16, LN16, swish
        const int j2 = lane & 15;
        float y2 = 0.f;
#pragma unroll
        for (int i = 0; i < 32; ++i) y2 = fmaf(hb[winb][i], sW[6144 + i * 16 + j2], y2);
        {
            float s = y2;
#pragma unroll
            for (int m = 8; m; m >>= 1) s += __shfl_xor(s, m);
            float mean = s * (1.f / 16.f);
            float d = y2 - mean;
            float vs = d * d;
#pragma unroll
            for (int m = 8; m; m >>= 1) vs += __shfl_xor(vs, m);
            y2 = d * rsqrtf(vs * (1.f / 16.f) + 1e-6f) * rs2[j2] + rb2[j2];
            y2 = swishf(y2);
        }
        if (lane < 16) hb[winb][lane] = y2;
        // layer 3: 16 -> 16, LN16, swish
        float y3 = 0.f;
#pragma unroll
        for (int i = 0; i < 16; ++i) y3 = fmaf(hb[winb][i], sW[6656 + i * 16 + j2], y3);
        {
            float s = y3;
#pragma unroll
            for (int m = 8; m; m >>= 1) s += __shfl_xor(s, m);
            float mean = s * (1.f / 16.f);
            float d = y3 - mean;
            float vs = d * d;
#pragma unroll
            for (int m = 8; m; m >>= 1) vs += __shfl_xor(vs, m);
            y3 = d * rsqrtf(vs * (1.f / 16.f) + 1e-6f) * rs3[j2] + rb3[j2];
            y3 = swishf(y3);
        }
        if (lane < 16) hb[winb][lane] = y3;
        // final: 16 -> 1, swish
        float p = (lane < 16) ? hb[winb][lane] * sW[6912 + lane] : 0.f;
#pragma unroll
        for (int m = 8; m; m >>= 1) p += __shfl_xor(p, m);
        if (lane == 0) out[n] = swishf(p);
    }
}

extern "C" void kernel_launch(void* const* d_in, const int* in_sizes, int n_in,
                              void* d_out, int out_size, void* d_ws, size_t ws_size,
                              hipStream_t stream)
{
    const float* nodes     = (const float*)d_in[0];
    const float* edges     = (const float*)d_in[1];
    const int*   senders   = (const int*)d_in[2];
    const int*   receivers = (const int*)d_in[3];
    // d_in[4] = mask (all true in this problem; where(mask,0,-inf) == 0) — ignored
    const float* Wq  = (const float*)d_in[5];
    const float* Wk  = (const float*)d_in[6];
    const float* Wa  = (const float*)d_in[7];
    const float* ln_s = (const float*)d_in[8];
    const float* ln_b = (const float*)d_in[9];
    const float* Wr0 = (const float*)d_in[10];
    const float* rs0 = (const float*)d_in[11];
    const float* rb0 = (const float*)d_in[12];
    const float* Wr1 = (const float*)d_in[13];
    const float* rs1 = (const float*)d_in[14];
    const float* rb1 = (const float*)d_in[15];
    const float* Wr2 = (const float*)d_in[16];
    const float* rs2 = (const float*)d_in[17];
    const float* rb2 = (const float*)d_in[18];
    const float* Wr3 = (const float*)d_in[19];
    const float* rs3 = (const float*)d_in[20];
    const float* rb3 = (const float*)d_in[21];
    const float* Wr4 = (const float*)d_in[22];
    float* out = (float*)d_out;

    // workspace layout:
    // x, q, k: N*64 floats each; counts, ctr: N ints; offsets: N+1 ints; sorted: E ints
    float* x       = (float*)d_ws;
    float* q       = x + (size_t)NN * 64;
    float* k       = q + (size_t)NN * 64;
    int*   counts  = (int*)(k + (size_t)NN * 64);
    int*   ctr     = counts + NN;
    int*   offsets = ctr + NN;
    int*   sorted  = offsets + NN + 1;

    hipMemcpyAsync(x, nodes, (size_t)NN * 64 * sizeof(float), hipMemcpyDeviceToDevice, stream);

    // ---- CSR by receiver (graph identical for all layers: build once) ----
    hipMemsetAsync(counts, 0, 2 * NN * sizeof(int), stream);  // counts + ctr
    hist_kernel<<<3125, 256, 0, stream>>>(receivers, counts);
    scan_kernel<<<1, 1024, 0, stream>>>(counts, offsets);
    scatter_kernel<<<3125, 256, 0, stream>>>(receivers, offsets, ctr, sorted);

    for (int l = 0; l < 4; ++l) {
        qk_kernel<<<1024, 256, 0, stream>>>(x, Wq + l * 4096, Wk + l * 4096, q, k);
        int lnidx = l < 3 ? l : 0;
        attn_kernel<<<12500, 256, 0, stream>>>(q, k, edges, senders, sorted, offsets,
                                               Wa + l * 65, x,
                                               ln_s + lnidx * 64, ln_b + lnidx * 64,
                                               l < 3 ? 1 : 0);
    }
    readout_kernel<<<2048, 256, 0, stream>>>(x, Wr0, rs0, rb0, Wr1, rs1, rb1,
                                             Wr2, rs2, rb2, Wr3, rs3, rb3, Wr4, out);
}

// Round 3
// 694.439 us; speedup vs baseline: 2.5587x; 1.4997x over previous
//
#include <hip/hip_runtime.h>

#define NN 50000
#define EE 800000

__device__ __forceinline__ float swishf(float v) {
    return v / (1.f + __expf(-v));
}

// ---------------- q/k projection: q = x @ Wq, k = x @ Wk (64x64 weights) ------
__global__ void __launch_bounds__(256) qk_kernel(
    const float* __restrict__ x, const float* __restrict__ Wq, const float* __restrict__ Wk,
    float* __restrict__ q, float* __restrict__ k)
{
    __shared__ float sWq[64 * 64];
    __shared__ float sWk[64 * 64];
    __shared__ float xrow[4][64];
    for (int i = threadIdx.x; i < 4096; i += 256) { sWq[i] = Wq[i]; sWk[i] = Wk[i]; }
    __syncthreads();
    const int lane = threadIdx.x & 63;
    const int winb = threadIdx.x >> 6;
    const int wave = (blockIdx.x * 256 + threadIdx.x) >> 6;
    const int nw = gridDim.x * 4;
    for (int row = wave; row < NN; row += nw) {
        xrow[winb][lane] = x[row * 64 + lane];
        float aq = 0.f, ak = 0.f;
#pragma unroll
        for (int b = 0; b < 64; ++b) {
            float xb = xrow[winb][b];
            aq = fmaf(xb, sWq[b * 64 + lane], aq);
            ak = fmaf(xb, sWk[b * 64 + lane], ak);
        }
        q[row * 64 + lane] = aq;
        k[row * 64 + lane] = ak;
    }
}

// ---------------- CSR build: histogram / scan / scatter ----------------------
__global__ void __launch_bounds__(256) hist_kernel(
    const int* __restrict__ receivers, int* __restrict__ counts)
{
    int e = blockIdx.x * 256 + threadIdx.x;
    int stride = gridDim.x * 256;
    for (; e < EE; e += stride) atomicAdd(counts + receivers[e], 1);
}

__global__ void __launch_bounds__(1024) scan_kernel(
    const int* __restrict__ counts, int* __restrict__ offsets)
{
    __shared__ int ts[1024];
    const int t = threadIdx.x;
    const int beg = t * 49;
    const int end = min(beg + 49, NN);
    int s = 0;
    for (int i = beg; i < end; ++i) s += counts[i];
    ts[t] = s;
    __syncthreads();
    for (int d = 1; d < 1024; d <<= 1) {
        int v = (t >= d) ? ts[t - d] : 0;
        __syncthreads();
        ts[t] += v;
        __syncthreads();
    }
    int ex = (t == 0) ? 0 : ts[t - 1];
    for (int i = beg; i < end; ++i) { offsets[i] = ex; ex += counts[i]; }
    if (t == 1023) offsets[NN] = ts[1023];
}

__global__ void __launch_bounds__(256) scatter_kernel(
    const int* __restrict__ receivers, const int* __restrict__ senders,
    const float* __restrict__ edges, const int* __restrict__ offsets,
    int* __restrict__ ctr, int* __restrict__ ssort, float* __restrict__ esort)
{
    int e = blockIdx.x * 256 + threadIdx.x;
    int stride = gridDim.x * 256;
    for (; e < EE; e += stride) {
        int r = receivers[e];
        int pos = atomicAdd(ctr + r, 1);
        int idx = offsets[r] + pos;
        ssort[idx] = senders[e];
        esort[idx] = edges[e];
    }
}

// ---------------- fused attention layer: wave per receiver -------------------
// 8 edges processed lane-parallel per step: lane = (edge e=lane>>3, chunk c=lane&7).
// Each lane covers dims [4c..4c+3] and [32+4c..32+4c+3] (one 128B line per
// row per load instr). Online softmax rescale amortized per 8-edge chunk.
// Gathered q rows staged in LDS and reused for the numerator in lane=dim layout.
__global__ void __launch_bounds__(256) attn_kernel(
    const float* __restrict__ q, const float* __restrict__ k,
    const int* __restrict__ ssort, const float* __restrict__ esort,
    const int* __restrict__ offsets, const float* __restrict__ Wa,
    float* __restrict__ x, const float* __restrict__ ln_s,
    const float* __restrict__ ln_b, int do_ln)
{
    __shared__ float sQ[4][8][68];   // padded stride 68 -> conflict-free
    __shared__ float sWb[4][8];
    const int lane = threadIdx.x & 63;
    const int winb = threadIdx.x >> 6;
    const int wave = (blockIdx.x * 256 + threadIdx.x) >> 6;
    const int nw = gridDim.x * 4;
    const int c = lane & 7;
    const int e = lane >> 3;
    const int ofs = c * 4;
    float wac0[4], wac1[4];
#pragma unroll
    for (int j = 0; j < 4; ++j) { wac0[j] = Wa[ofs + j]; wac1[j] = Wa[32 + ofs + j]; }
    const float wa64 = Wa[64];
    const float lnsv = ln_s[lane], lnbv = ln_b[lane];

    for (int r = wave; r < NN; r += nw) {
        const float4 ka = *(const float4*)(k + (size_t)r * 64 + ofs);
        const float4 kb = *(const float4*)(k + (size_t)r * 64 + 32 + ofs);
        const int beg = offsets[r], end = offsets[r + 1];
        float m = -3.0e38f, denp = 0.f, acc = 0.f;
        for (int i0 = beg; i0 < end; i0 += 8) {
            const int myi = i0 + e;
            const bool valid = myi < end;
            int s = 0; float ea = 0.f;
            if (valid) { s = ssort[myi]; ea = esort[myi]; }
            const float4 qa = *(const float4*)(q + (size_t)s * 64 + ofs);
            const float4 qb = *(const float4*)(q + (size_t)s * 64 + 32 + ofs);
            float p = 0.f;
            p = fmaf(swishf(qa.x + ka.x), wac0[0], p);
            p = fmaf(swishf(qa.y + ka.y), wac0[1], p);
            p = fmaf(swishf(qa.z + ka.z), wac0[2], p);
            p = fmaf(swishf(qa.w + ka.w), wac0[3], p);
            p = fmaf(swishf(qb.x + kb.x), wac1[0], p);
            p = fmaf(swishf(qb.y + kb.y), wac1[1], p);
            p = fmaf(swishf(qb.z + kb.z), wac1[2], p);
            p = fmaf(swishf(qb.w + kb.w), wac1[3], p);
            // reduce partial dot across the 8 dim-chunks (lanes differing in c)
            p += __shfl_xor(p, 1);
            p += __shfl_xor(p, 2);
            p += __shfl_xor(p, 4);
            const float logit = valid ? fmaf(ea, wa64, p) : -3.0e38f;
            // chunk max across the 8 edge slots (lanes differing in e)
            float cm = logit;
            cm = fmaxf(cm, __shfl_xor(cm, 8));
            cm = fmaxf(cm, __shfl_xor(cm, 16));
            cm = fmaxf(cm, __shfl_xor(cm, 32));
            if (cm > m) {                       // wave-uniform
                const float sc = __expf(m - cm);
                denp *= sc; acc *= sc; m = cm;
            }
            const float w = valid ? __expf(logit - m) : 0.f;
            denp += w;
            // stage q rows + w for the lane=dim numerator pass
            *(float4*)(&sQ[winb][e][ofs]) = qa;
            *(float4*)(&sQ[winb][e][32 + ofs]) = qb;
            if (c == 0) sWb[winb][e] = w;
            __builtin_amdgcn_wave_barrier();
#pragma unroll
            for (int j = 0; j < 8; ++j)
                acc = fmaf(sWb[winb][j], sQ[winb][j][lane], acc);
            __builtin_amdgcn_wave_barrier();
        }
        // each edge's w was accumulated by all 8 lanes of its group
        float den = denp;
#pragma unroll
        for (int msk = 32; msk; msk >>= 1) den += __shfl_xor(den, msk);
        den *= 0.125f;
        float v = den > 0.f ? acc / den : 0.f;
        float nv = swishf(v) + x[(size_t)r * 64 + lane];
        if (do_ln) {
            float sum = nv;
#pragma unroll
            for (int msk = 32; msk; msk >>= 1) sum += __shfl_xor(sum, msk);
            const float mean = sum * (1.f / 64.f);
            const float d = nv - mean;
            float vs = d * d;
#pragma unroll
            for (int msk = 32; msk; msk >>= 1) vs += __shfl_xor(vs, msk);
            nv = d * rsqrtf(vs * (1.f / 64.f) + 1e-6f) * lnsv + lnbv;
        }
        x[(size_t)r * 64 + lane] = nv;
    }
}

// ---------------- fused readout MLP: 64->64->32->16->16->1 -------------------
__global__ void __launch_bounds__(256) readout_kernel(
    const float* __restrict__ x,
    const float* __restrict__ W0, const float* __restrict__ rs0, const float* __restrict__ rb0,
    const float* __restrict__ W1, const float* __restrict__ rs1, const float* __restrict__ rb1,
    const float* __restrict__ W2, const float* __restrict__ rs2, const float* __restrict__ rb2,
    const float* __restrict__ W3, const float* __restrict__ rs3, const float* __restrict__ rb3,
    const float* __restrict__ W4, float* __restrict__ out)
{
    __shared__ float sW[6928];
    __shared__ float hb[4][64];
    for (int i = threadIdx.x; i < 4096; i += 256) sW[i] = W0[i];
    for (int i = threadIdx.x; i < 2048; i += 256) sW[4096 + i] = W1[i];
    for (int i = threadIdx.x; i < 512; i += 256) sW[6144 + i] = W2[i];
    for (int i = threadIdx.x; i < 256; i += 256) sW[6656 + i] = W3[i];
    if (threadIdx.x < 16) sW[6912 + threadIdx.x] = W4[threadIdx.x];
    __syncthreads();
    const int lane = threadIdx.x & 63;
    const int winb = threadIdx.x >> 6;
    const int wave = (blockIdx.x * 256 + threadIdx.x) >> 6;
    const int nw = gridDim.x * 4;
    for (int n = wave; n < NN; n += nw) {
        hb[winb][lane] = x[(size_t)n * 64 + lane];
        float y = 0.f;
#pragma unroll
        for (int i = 0; i < 64; ++i) y = fmaf(hb[winb][i], sW[i * 64 + lane], y);
        {
            float s = y;
#pragma unroll
            for (int m = 32; m; m >>= 1) s += __shfl_xor(s, m);
            float mean = s * (1.f / 64.f);
            float d = y - mean;
            float vs = d * d;
#pragma unroll
            for (int m = 32; m; m >>= 1) vs += __shfl_xor(vs, m);
            y = d * rsqrtf(vs * (1.f / 64.f) + 1e-6f) * rs0[lane] + rb0[lane];
            y = swishf(y);
        }
        hb[winb][lane] = y;
        const int j1 = lane & 31;
        float y1 = 0.f;
#pragma unroll
        for (int i = 0; i < 64; ++i) y1 = fmaf(hb[winb][i], sW[4096 + i * 32 + j1], y1);
        {
            float s = y1;
#pragma unroll
            for (int m = 16; m; m >>= 1) s += __shfl_xor(s, m);
            float mean = s * (1.f / 32.f);
            float d = y1 - mean;
            float vs = d * d;
#pragma unroll
            for (int m = 16; m; m >>= 1) vs += __shfl_xor(vs, m);
            y1 = d * rsqrtf(vs * (1.f / 32.f) + 1e-6f) * rs1[j1] + rb1[j1];
            y1 = swishf(y1);
        }
        if (lane < 32) hb[winb][lane] = y1;
        const int j2 = lane & 15;
        float y2 = 0.f;
#pragma unroll
        for (int i = 0; i < 32; ++i) y2 = fmaf(hb[winb][i], sW[6144 + i * 16 + j2], y2);
        {
            float s = y2;
#pragma unroll
            for (int m = 8; m; m >>= 1) s += __shfl_xor(s, m);
            float mean = s * (1.f / 16.f);
            float d = y2 - mean;
            float vs = d * d;
#pragma unroll
            for (int m = 8; m; m >>= 1) vs += __shfl_xor(vs, m);
            y2 = d * rsqrtf(vs * (1.f / 16.f) + 1e-6f) * rs2[j2] + rb2[j2];
            y2 = swishf(y2);
        }
        if (lane < 16) hb[winb][lane] = y2;
        float y3 = 0.f;
#pragma unroll
        for (int i = 0; i < 16; ++i) y3 = fmaf(hb[winb][i], sW[6656 + i * 16 + j2], y3);
        {
            float s = y3;
#pragma unroll
            for (int m = 8; m; m >>= 1) s += __shfl_xor(s, m);
            float mean = s * (1.f / 16.f);
            float d = y3 - mean;
            float vs = d * d;
#pragma unroll
            for (int m = 8; m; m >>= 1) vs += __shfl_xor(vs, m);
            y3 = d * rsqrtf(vs * (1.f / 16.f) + 1e-6f) * rs3[j2] + rb3[j2];
            y3 = swishf(y3);
        }
        if (lane < 16) hb[winb][lane] = y3;
        float p = (lane < 16) ? hb[winb][lane] * sW[6912 + lane] : 0.f;
#pragma unroll
        for (int m = 8; m; m >>= 1) p += __shfl_xor(p, m);
        if (lane == 0) out[n] = swishf(p);
    }
}

extern "C" void kernel_launch(void* const* d_in, const int* in_sizes, int n_in,
                              void* d_out, int out_size, void* d_ws, size_t ws_size,
                              hipStream_t stream)
{
    const float* nodes     = (const float*)d_in[0];
    const float* edges     = (const float*)d_in[1];
    const int*   senders   = (const int*)d_in[2];
    const int*   receivers = (const int*)d_in[3];
    // d_in[4] = mask (all true; where(mask,0,-inf)==0) — ignored
    const float* Wq  = (const float*)d_in[5];
    const float* Wk  = (const float*)d_in[6];
    const float* Wa  = (const float*)d_in[7];
    const float* ln_s = (const float*)d_in[8];
    const float* ln_b = (const float*)d_in[9];
    const float* Wr0 = (const float*)d_in[10];
    const float* rs0 = (const float*)d_in[11];
    const float* rb0 = (const float*)d_in[12];
    const float* Wr1 = (const float*)d_in[13];
    const float* rs1 = (const float*)d_in[14];
    const float* rb1 = (const float*)d_in[15];
    const float* Wr2 = (const float*)d_in[16];
    const float* rs2 = (const float*)d_in[17];
    const float* rb2 = (const float*)d_in[18];
    const float* Wr3 = (const float*)d_in[19];
    const float* rs3 = (const float*)d_in[20];
    const float* rb3 = (const float*)d_in[21];
    const float* Wr4 = (const float*)d_in[22];
    float* out = (float*)d_out;

    // workspace: x,q,k: N*64 f32; counts,ctr: N i32; offsets: N+1; ssort: E i32; esort: E f32
    float* x       = (float*)d_ws;
    float* q       = x + (size_t)NN * 64;
    float* k       = q + (size_t)NN * 64;
    int*   counts  = (int*)(k + (size_t)NN * 64);
    int*   ctr     = counts + NN;
    int*   offsets = ctr + NN;
    int*   ssort   = offsets + NN + 1;
    float* esort   = (float*)(ssort + EE);

    hipMemcpyAsync(x, nodes, (size_t)NN * 64 * sizeof(float), hipMemcpyDeviceToDevice, stream);

    // ---- CSR by receiver (graph identical across layers: build once) ----
    hipMemsetAsync(counts, 0, 2 * NN * sizeof(int), stream);
    hist_kernel<<<3125, 256, 0, stream>>>(receivers, counts);
    scan_kernel<<<1, 1024, 0, stream>>>(counts, offsets);
    scatter_kernel<<<3125, 256, 0, stream>>>(receivers, senders, edges, offsets, ctr, ssort, esort);

    for (int l = 0; l < 4; ++l) {
        qk_kernel<<<1024, 256, 0, stream>>>(x, Wq + l * 4096, Wk + l * 4096, q, k);
        int lnidx = l < 3 ? l : 0;
        attn_kernel<<<3125, 256, 0, stream>>>(q, k, ssort, esort, offsets,
                                              Wa + l * 65, x,
                                              ln_s + lnidx * 64, ln_b + lnidx * 64,
                                              l < 3 ? 1 : 0);
    }
    readout_kernel<<<2048, 256, 0, stream>>>(x, Wr0, rs0, rb0, Wr1, rs1, rb1,
                                             Wr2, rs2, rb2, Wr3, rs3, rb3, Wr4, out);
}

// Round 4
// 639.772 us; speedup vs baseline: 2.7773x; 1.0854x over previous
//
#include <hip/hip_runtime.h>

#define NN 50000
#define EE 800000

typedef unsigned short ushort_t;
typedef unsigned int uint_t;

__device__ __forceinline__ float swishf(float v) {
    return v / (1.f + __expf(-v));
}
__device__ __forceinline__ ushort_t f2bf(float f) {
    uint_t u = __float_as_uint(f);
    uint_t r = (u + 0x7fffu + ((u >> 16) & 1u)) >> 16;
    return (ushort_t)r;
}
__device__ __forceinline__ float bf2f(ushort_t h) {
    return __uint_as_float(((uint_t)h) << 16);
}

// ---------------- q/k projection: q(bf16) = x @ Wq, k(f32) = x @ Wk ----------
__global__ void __launch_bounds__(256) qk_kernel(
    const float* __restrict__ x, const float* __restrict__ Wq, const float* __restrict__ Wk,
    ushort_t* __restrict__ qbf, float* __restrict__ k)
{
    __shared__ float sWq[64 * 64];
    __shared__ float sWk[64 * 64];
    __shared__ float xrow[4][64];
    for (int i = threadIdx.x; i < 4096; i += 256) { sWq[i] = Wq[i]; sWk[i] = Wk[i]; }
    __syncthreads();
    const int lane = threadIdx.x & 63;
    const int winb = threadIdx.x >> 6;
    const int wave = (blockIdx.x * 256 + threadIdx.x) >> 6;
    const int nw = gridDim.x * 4;
    for (int row = wave; row < NN; row += nw) {
        xrow[winb][lane] = x[row * 64 + lane];
        float aq = 0.f, ak = 0.f;
#pragma unroll
        for (int b = 0; b < 64; ++b) {
            float xb = xrow[winb][b];
            aq = fmaf(xb, sWq[b * 64 + lane], aq);
            ak = fmaf(xb, sWk[b * 64 + lane], ak);
        }
        qbf[row * 64 + lane] = f2bf(aq);
        k[row * 64 + lane] = ak;
    }
}

// ---------------- CSR build: histogram / scan / scatter ----------------------
__global__ void __launch_bounds__(256) hist_kernel(
    const int* __restrict__ receivers, int* __restrict__ counts)
{
    int e = blockIdx.x * 256 + threadIdx.x;
    int stride = gridDim.x * 256;
    for (; e < EE; e += stride) atomicAdd(counts + receivers[e], 1);
}

__global__ void __launch_bounds__(1024) scan_kernel(
    const int* __restrict__ counts, int* __restrict__ offsets)
{
    __shared__ int ts[1024];
    const int t = threadIdx.x;
    const int beg = t * 49;
    const int end = min(beg + 49, NN);
    int s = 0;
    for (int i = beg; i < end; ++i) s += counts[i];
    ts[t] = s;
    __syncthreads();
    for (int d = 1; d < 1024; d <<= 1) {
        int v = (t >= d) ? ts[t - d] : 0;
        __syncthreads();
        ts[t] += v;
        __syncthreads();
    }
    int ex = (t == 0) ? 0 : ts[t - 1];
    for (int i = beg; i < end; ++i) { offsets[i] = ex; ex += counts[i]; }
    if (t == 1023) offsets[NN] = ts[1023];
}

__global__ void __launch_bounds__(256) scatter_kernel(
    const int* __restrict__ receivers, const int* __restrict__ senders,
    const float* __restrict__ edges, const int* __restrict__ offsets,
    int* __restrict__ ctr, int* __restrict__ ssort, float* __restrict__ esort)
{
    int e = blockIdx.x * 256 + threadIdx.x;
    int stride = gridDim.x * 256;
    for (; e < EE; e += stride) {
        int r = receivers[e];
        int pos = atomicAdd(ctr + r, 1);
        int idx = offsets[r] + pos;
        ssort[idx] = senders[e];
        esort[idx] = edges[e];
    }
}

// ---------------- fused attention layer: wave per receiver -------------------
// q stored bf16: one dwordx4 (8 dims) per lane per edge. lane = (e=lane>>3,
// c=lane&7), lane covers dims [8c..8c+7]. Online softmax rescale per 8-edge
// chunk; gathered bf16 rows staged in LDS for the lane=dim numerator pass.
__global__ void __launch_bounds__(256) attn_kernel(
    const ushort_t* __restrict__ qbf, const float* __restrict__ k,
    const int* __restrict__ ssort, const float* __restrict__ esort,
    const int* __restrict__ offsets, const float* __restrict__ Wa,
    float* __restrict__ x, const float* __restrict__ ln_s,
    const float* __restrict__ ln_b, int do_ln)
{
    __shared__ ushort_t sQ[4][8][64];
    __shared__ float sWb[4][8];
    const int lane = threadIdx.x & 63;
    const int winb = threadIdx.x >> 6;
    const int wave = (blockIdx.x * 256 + threadIdx.x) >> 6;
    const int nw = gridDim.x * 4;
    const int c = lane & 7;
    const int e = lane >> 3;
    const int ofs = c * 8;
    float wac[8];
#pragma unroll
    for (int j = 0; j < 8; ++j) wac[j] = Wa[ofs + j];
    const float wa64 = Wa[64];
    const float lnsv = ln_s[lane], lnbv = ln_b[lane];

    for (int r = wave; r < NN; r += nw) {
        float kc[8];
        {
            const float4 k0 = *(const float4*)(k + (size_t)r * 64 + ofs);
            const float4 k1 = *(const float4*)(k + (size_t)r * 64 + ofs + 4);
            kc[0] = k0.x; kc[1] = k0.y; kc[2] = k0.z; kc[3] = k0.w;
            kc[4] = k1.x; kc[5] = k1.y; kc[6] = k1.z; kc[7] = k1.w;
        }
        const int beg = offsets[r], end = offsets[r + 1];
        float m = -3.0e38f, denp = 0.f, acc = 0.f;
        for (int i0 = beg; i0 < end; i0 += 8) {
            const int myi = i0 + e;
            const bool valid = myi < end;
            int s = 0; float ea = 0.f;
            if (valid) { s = ssort[myi]; ea = esort[myi]; }
            const uint4 qraw = *(const uint4*)(qbf + (size_t)s * 64 + ofs);
            float qv[8];
            qv[0] = __uint_as_float(qraw.x << 16);
            qv[1] = __uint_as_float(qraw.x & 0xFFFF0000u);
            qv[2] = __uint_as_float(qraw.y << 16);
            qv[3] = __uint_as_float(qraw.y & 0xFFFF0000u);
            qv[4] = __uint_as_float(qraw.z << 16);
            qv[5] = __uint_as_float(qraw.z & 0xFFFF0000u);
            qv[6] = __uint_as_float(qraw.w << 16);
            qv[7] = __uint_as_float(qraw.w & 0xFFFF0000u);
            float p = 0.f;
#pragma unroll
            for (int j = 0; j < 8; ++j) p = fmaf(swishf(qv[j] + kc[j]), wac[j], p);
            // reduce partial dot across the 8 dim-chunks
            p += __shfl_xor(p, 1);
            p += __shfl_xor(p, 2);
            p += __shfl_xor(p, 4);
            const float logit = valid ? fmaf(ea, wa64, p) : -3.0e38f;
            // chunk max across the 8 edge slots
            float cm = logit;
            cm = fmaxf(cm, __shfl_xor(cm, 8));
            cm = fmaxf(cm, __shfl_xor(cm, 16));
            cm = fmaxf(cm, __shfl_xor(cm, 32));
            if (cm > m) {                        // wave-uniform
                const float sc = __expf(m - cm);
                denp *= sc; acc *= sc; m = cm;
            }
            const float w = valid ? __expf(logit - m) : 0.f;
            denp += w;
            // stage bf16 q rows + w for the lane=dim numerator pass
            *(uint4*)(&sQ[winb][e][ofs]) = qraw;
            if (c == 0) sWb[winb][e] = w;
            __builtin_amdgcn_wave_barrier();
#pragma unroll
            for (int j = 0; j < 8; ++j)
                acc = fmaf(sWb[winb][j], bf2f(sQ[winb][j][lane]), acc);
            __builtin_amdgcn_wave_barrier();
        }
        float den = denp;
#pragma unroll
        for (int msk = 32; msk; msk >>= 1) den += __shfl_xor(den, msk);
        den *= 0.125f;
        float v = den > 0.f ? acc / den : 0.f;
        float nv = swishf(v) + x[(size_t)r * 64 + lane];
        if (do_ln) {
            float sum = nv;
#pragma unroll
            for (int msk = 32; msk; msk >>= 1) sum += __shfl_xor(sum, msk);
            const float mean = sum * (1.f / 64.f);
            const float d = nv - mean;
            float vs = d * d;
#pragma unroll
            for (int msk = 32; msk; msk >>= 1) vs += __shfl_xor(vs, msk);
            nv = d * rsqrtf(vs * (1.f / 64.f) + 1e-6f) * lnsv + lnbv;
        }
        x[(size_t)r * 64 + lane] = nv;
    }
}

// ---------------- readout MLP: one THREAD per node, all in registers ---------
template<int In, int Out>
__device__ __forceinline__ void dense(const float* __restrict__ h, float* __restrict__ y,
                                      const float* __restrict__ W)
{
#pragma unroll
    for (int j = 0; j < Out; ++j) y[j] = 0.f;
#pragma unroll
    for (int i = 0; i < In; ++i) {
        const float hi = h[i];
#pragma unroll
        for (int j = 0; j < Out; ++j) y[j] = fmaf(hi, W[i * Out + j], y[j]);
    }
}

template<int Dim>
__device__ __forceinline__ void ln_swish(float* __restrict__ v,
                                         const float* __restrict__ s,
                                         const float* __restrict__ b)
{
    float mean = 0.f;
#pragma unroll
    for (int d = 0; d < Dim; ++d) mean += v[d];
    mean *= (1.f / Dim);
    float var = 0.f;
#pragma unroll
    for (int d = 0; d < Dim; ++d) { const float t = v[d] - mean; var = fmaf(t, t, var); }
    const float inv = rsqrtf(var * (1.f / Dim) + 1e-6f);
#pragma unroll
    for (int d = 0; d < Dim; ++d) v[d] = swishf((v[d] - mean) * inv * s[d] + b[d]);
}

__global__ void __launch_bounds__(256) readout_kernel(
    const float* __restrict__ x,
    const float* __restrict__ W0, const float* __restrict__ rs0, const float* __restrict__ rb0,
    const float* __restrict__ W1, const float* __restrict__ rs1, const float* __restrict__ rb1,
    const float* __restrict__ W2, const float* __restrict__ rs2, const float* __restrict__ rb2,
    const float* __restrict__ W3, const float* __restrict__ rs3, const float* __restrict__ rb3,
    const float* __restrict__ W4, float* __restrict__ out)
{
    const int n = blockIdx.x * 256 + threadIdx.x;
    if (n >= NN) return;
    float h[64];
#pragma unroll
    for (int i = 0; i < 64; ++i) h[i] = x[(size_t)n * 64 + i];
    float y[64];
    dense<64, 64>(h, y, W0); ln_swish<64>(y, rs0, rb0);
    float z[32];
    dense<64, 32>(y, z, W1); ln_swish<32>(z, rs1, rb1);
    float u[16];
    dense<32, 16>(z, u, W2); ln_swish<16>(u, rs2, rb2);
    float v[16];
    dense<16, 16>(u, v, W3); ln_swish<16>(v, rs3, rb3);
    float p = 0.f;
#pragma unroll
    for (int i = 0; i < 16; ++i) p = fmaf(v[i], W4[i], p);
    out[n] = swishf(p);
}

extern "C" void kernel_launch(void* const* d_in, const int* in_sizes, int n_in,
                              void* d_out, int out_size, void* d_ws, size_t ws_size,
                              hipStream_t stream)
{
    const float* nodes     = (const float*)d_in[0];
    const float* edges     = (const float*)d_in[1];
    const int*   senders   = (const int*)d_in[2];
    const int*   receivers = (const int*)d_in[3];
    // d_in[4] = mask (all true; where(mask,0,-inf)==0) — ignored
    const float* Wq  = (const float*)d_in[5];
    const float* Wk  = (const float*)d_in[6];
    const float* Wa  = (const float*)d_in[7];
    const float* ln_s = (const float*)d_in[8];
    const float* ln_b = (const float*)d_in[9];
    const float* Wr0 = (const float*)d_in[10];
    const float* rs0 = (const float*)d_in[11];
    const float* rb0 = (const float*)d_in[12];
    const float* Wr1 = (const float*)d_in[13];
    const float* rs1 = (const float*)d_in[14];
    const float* rb1 = (const float*)d_in[15];
    const float* Wr2 = (const float*)d_in[16];
    const float* rs2 = (const float*)d_in[17];
    const float* rb2 = (const float*)d_in[18];
    const float* Wr3 = (const float*)d_in[19];
    const float* rs3 = (const float*)d_in[20];
    const float* rb3 = (const float*)d_in[21];
    const float* Wr4 = (const float*)d_in[22];
    float* out = (float*)d_out;

    // workspace: x (N*64 f32), k (N*64 f32), qbf (N*64 bf16),
    //            counts,ctr (N i32), offsets (N+1), ssort (E i32), esort (E f32)
    float*    x       = (float*)d_ws;
    float*    k       = x + (size_t)NN * 64;
    ushort_t* qbf     = (ushort_t*)(k + (size_t)NN * 64);
    int*      counts  = (int*)(qbf + (size_t)NN * 64);
    int*      ctr     = counts + NN;
    int*      offsets = ctr + NN;
    int*      ssort   = offsets + NN + 1;
    float*    esort   = (float*)(ssort + EE);

    hipMemcpyAsync(x, nodes, (size_t)NN * 64 * sizeof(float), hipMemcpyDeviceToDevice, stream);

    // ---- CSR by receiver (graph identical across layers: build once) ----
    hipMemsetAsync(counts, 0, 2 * NN * sizeof(int), stream);
    hist_kernel<<<3125, 256, 0, stream>>>(receivers, counts);
    scan_kernel<<<1, 1024, 0, stream>>>(counts, offsets);
    scatter_kernel<<<3125, 256, 0, stream>>>(receivers, senders, edges, offsets, ctr, ssort, esort);

    for (int l = 0; l < 4; ++l) {
        qk_kernel<<<1024, 256, 0, stream>>>(x, Wq + l * 4096, Wk + l * 4096, qbf, k);
        int lnidx = l < 3 ? l : 0;
        attn_kernel<<<3125, 256, 0, stream>>>(qbf, k, ssort, esort, offsets,
                                              Wa + l * 65, x,
                                              ln_s + lnidx * 64, ln_b + lnidx * 64,
                                              l < 3 ? 1 : 0);
    }
    readout_kernel<<<196, 256, 0, stream>>>(x, Wr0, rs0, rb0, Wr1, rs1, rb1,
                                            Wr2, rs2, rb2, Wr3, rs3, rb3, Wr4, out);
}